// Round 1
// baseline (908.503 us; speedup 1.0000x reference)
//
#include <hip/hip_runtime.h>

#define N_AG 256
#define HDIM 1024
#define NINP 512
#define EDG  65280

struct GCfg {
  const float* B;
  float* C;
  const float* bias;
  float* C2;
  int ldb;
  int ldc;
  int ncols;
  int flags; // 1=modeT, 2=tanh, 4=bias, 8=dual-store
};

// wd[k] = W2[k][1]-W2[k][0]; bd = b2[1]-b2[0]
__global__ __launch_bounds__(512) void prep_k(const float* w2a, const float* b2a,
                                              const float* w2b, const float* b2b,
                                              float* wd1, float* wd2, float* bd) {
  int z = blockIdx.x;
  const float* W2 = z ? w2b : w2a;
  float* wd = z ? wd2 : wd1;
  int t = threadIdx.x;
  if (t < 512) wd[t] = W2[2*t+1] - W2[2*t];
  if (t == 0) {
    const float* b2 = z ? b2b : b2a;
    bd[z] = b2[1] - b2[0];
  }
}

// x [256][512] -> xT [512][256]
__global__ __launch_bounds__(256) void transpose_k(const float* __restrict__ x, float* __restrict__ xT) {
  __shared__ float tile[32][33];
  int tx = threadIdx.x;       // 0..31
  int ty = threadIdx.y;       // 0..7
  int k0 = blockIdx.x*32, m0 = blockIdx.y*32;
  #pragma unroll
  for (int i=0;i<4;++i) tile[ty*4+i][tx] = x[(size_t)(m0+ty*4+i)*NINP + k0+tx];
  __syncthreads();
  #pragma unroll
  for (int i=0;i<4;++i) xT[(size_t)(k0+ty*4+i)*N_AG + m0+tx] = tile[tx][ty*4+i];
}

// Computes CT[n][m] = sum_k AT[k][m]*B[k][n] (+bias[n]) (tanh) for one of 3 cfgs (blockIdx.z).
// Wave = 64 m-lanes x 4 n-cols; block = 4 waves (16 n); grid (4, 64, nz).
// A-column read coalesced per-lane; B-row is wave-uniform -> scalar loads.
__global__ __launch_bounds__(256) void gemm_k(const float* __restrict__ AT, int K,
                                              GCfg c0, GCfg c1, GCfg c2) {
  GCfg c = (blockIdx.z==0) ? c0 : (blockIdx.z==1 ? c1 : c2);
  int lane = threadIdx.x & 63;
  int wv = __builtin_amdgcn_readfirstlane(threadIdx.x >> 6);
  int m  = blockIdx.x*64 + lane;
  int n0 = blockIdx.y*16 + wv*4;
  if (n0 >= c.ncols) return;
  const float* __restrict__ Ap = AT + m;
  const float* __restrict__ Bp = c.B + n0;
  const int ldb = c.ldb;
  float a0=0.f,a1=0.f,a2=0.f,a3=0.f;
  for (int k=0; k<K; k+=16) {
    #pragma unroll
    for (int u=0; u<16; ++u) {
      float av = Ap[(size_t)(k+u)*N_AG];
      const float4 bv = *reinterpret_cast<const float4*>(Bp + (size_t)(k+u)*ldb);
      a0 = fmaf(av, bv.x, a0);
      a1 = fmaf(av, bv.y, a1);
      a2 = fmaf(av, bv.z, a2);
      a3 = fmaf(av, bv.w, a3);
    }
  }
  if (c.flags & 4) {
    const float4 bb = *reinterpret_cast<const float4*>(c.bias + n0);
    a0+=bb.x; a1+=bb.y; a2+=bb.z; a3+=bb.w;
  }
  if (c.flags & 2) { a0=tanhf(a0); a1=tanhf(a1); a2=tanhf(a2); a3=tanhf(a3); }
  if (c.flags & 1) {
    float* C = c.C + (size_t)n0*N_AG + m;
    C[0]=a0; C[N_AG]=a1; C[2*N_AG]=a2; C[3*N_AG]=a3;
    if (c.flags & 8) {
      float* C2 = c.C2 + (size_t)n0*N_AG + m;
      C2[0]=a0; C2[N_AG]=a1; C2[2*N_AG]=a2; C2[3*N_AG]=a3;
    }
  } else {
    float4 o; o.x=a0; o.y=a1; o.z=a2; o.w=a3;
    *reinterpret_cast<float4*>(c.C + (size_t)m*c.ldc + n0) = o;
  }
}

// hOut[n][m] = tanh(xeT[n][m] + sum_k hT[k][m]*Wf[k][n] + sum_k cT[k][m]*Wc[k][n] + bf[n] + bc[n])
__global__ __launch_bounds__(256) void combine_k(const float* __restrict__ hT, const float* __restrict__ Wf,
    const float* __restrict__ cT, const float* __restrict__ Wc,
    const float* __restrict__ xeT, const float* __restrict__ bfp, const float* __restrict__ bcp,
    float* __restrict__ hOut) {
  int lane = threadIdx.x & 63;
  int wv = __builtin_amdgcn_readfirstlane(threadIdx.x >> 6);
  int m  = blockIdx.x*64 + lane;
  int n0 = blockIdx.y*16 + wv*4;
  float a0=0.f,a1=0.f,a2=0.f,a3=0.f;
  for (int k=0;k<HDIM;k+=16) {
    #pragma unroll
    for (int u=0;u<16;++u) {
      float av = hT[(size_t)(k+u)*N_AG + m];
      const float4 bv = *reinterpret_cast<const float4*>(Wf + (size_t)(k+u)*HDIM + n0);
      a0=fmaf(av,bv.x,a0); a1=fmaf(av,bv.y,a1); a2=fmaf(av,bv.z,a2); a3=fmaf(av,bv.w,a3);
    }
  }
  for (int k=0;k<HDIM;k+=16) {
    #pragma unroll
    for (int u=0;u<16;++u) {
      float av = cT[(size_t)(k+u)*N_AG + m];
      const float4 bv = *reinterpret_cast<const float4*>(Wc + (size_t)(k+u)*HDIM + n0);
      a0=fmaf(av,bv.x,a0); a1=fmaf(av,bv.y,a1); a2=fmaf(av,bv.z,a2); a3=fmaf(av,bv.w,a3);
    }
  }
  float r0 = a0 + xeT[(size_t)(n0+0)*N_AG+m] + bfp[n0+0] + bcp[n0+0];
  float r1 = a1 + xeT[(size_t)(n0+1)*N_AG+m] + bfp[n0+1] + bcp[n0+1];
  float r2 = a2 + xeT[(size_t)(n0+2)*N_AG+m] + bfp[n0+2] + bcp[n0+2];
  float r3 = a3 + xeT[(size_t)(n0+3)*N_AG+m] + bfp[n0+3] + bcp[n0+3];
  float* C = hOut + (size_t)n0*N_AG + m;
  C[0]=tanhf(r0); C[N_AG]=tanhf(r1); C[2*N_AG]=tanhf(r2); C[3*N_AG]=tanhf(r3);
}

// AdjT[s][d] = (d==s) ? 1 : 1[ sum_k relu(psb[s][k]+pdT[k][d])*wd[k] + bd + g1-g0 > 0 ]
// block: 2 src x 128 dst; grid (128, 2). psb/wd reads wave-uniform -> scalar.
__global__ __launch_bounds__(256) void edge_k(const float* __restrict__ psb,
    const float* __restrict__ pdT, const float* __restrict__ wd,
    const float* __restrict__ bdp, const float* __restrict__ g,
    float* __restrict__ AdjT) {
  int t = threadIdx.x;
  int s = blockIdx.x*2 + __builtin_amdgcn_readfirstlane(t >> 7);
  int d = blockIdx.y*128 + (t & 127);
  const float* __restrict__ ps = psb + (size_t)s*512;
  float acc = 0.f;
  #pragma unroll 8
  for (int k=0;k<512;++k) {
    float pv = ps[k];
    float a  = pdT[(size_t)k*N_AG + d];
    acc = fmaf(fmaxf(pv + a, 0.f), wd[k], acc);
  }
  int e = (d==s) ? 0 : (s*255 + d - (d>s ? 1 : 0));
  float g0 = g[2*e], g1 = g[2*e+1];
  float val = (acc + bdp[0] + g1 - g0) > 0.f ? 1.f : 0.f;
  if (d==s) val = 1.f;
  AdjT[(size_t)s*N_AG + d] = val;
}

// out init: a_mean=ba, a_log_std=ls, std=exp(ls), value=bv
__global__ __launch_bounds__(256) void outinit_k(float* out, const float* ba, const float* ls, const float* bvp) {
  int t = blockIdx.x*256 + threadIdx.x;
  if (t < 2048) out[t] = ba[t & 7];
  else if (t < 4096) out[t] = ls[t & 7];
  else if (t < 6144) out[t] = expf(ls[t & 7]);
  else if (t < 6400) out[t] = bvp[0];
}

// partial dot over c-chunk: out[m*8+j] += sum hT[c][m]*Wa[c][j]; out[6144+m] += sum hT[c][m]*Wv[c]
__global__ __launch_bounds__(64) void outpart_k(const float* __restrict__ hT, const float* __restrict__ Wa,
                                                const float* __restrict__ Wv, float* out) {
  int m = blockIdx.x*64 + threadIdx.x;
  int c0 = blockIdx.y*64;
  float acc[8] = {0,0,0,0,0,0,0,0};
  float av = 0.f;
  for (int c=c0; c<c0+64; ++c) {
    float h = hT[(size_t)c*N_AG + m];
    const float* wa = Wa + (size_t)c*8;
    #pragma unroll
    for (int j=0;j<8;++j) acc[j] = fmaf(h, wa[j], acc[j]);
    av = fmaf(h, Wv[c], av);
  }
  #pragma unroll
  for (int j=0;j<8;++j) atomicAdd(&out[m*8+j], acc[j]);
  atomicAdd(&out[6144+m], av);
}

extern "C" void kernel_launch(void* const* d_in, const int* in_sizes, int n_in,
                              void* d_out, int out_size, void* d_ws, size_t ws_size,
                              hipStream_t stream) {
  const float* x     = (const float*)d_in[0];
  const float* gum   = (const float*)d_in[1];
  const float* W_enc = (const float*)d_in[2];
  const float* b_enc = (const float*)d_in[3];
  const float* ha1W1 = (const float*)d_in[4];
  const float* ha1b1 = (const float*)d_in[5];
  const float* ha1W2 = (const float*)d_in[6];
  const float* ha1b2 = (const float*)d_in[7];
  const float* ha2W1 = (const float*)d_in[8];
  const float* ha2b1 = (const float*)d_in[9];
  const float* ha2W2 = (const float*)d_in[10];
  const float* ha2b2 = (const float*)d_in[11];
  const float* g1W = (const float*)d_in[12];
  const float* g1b = (const float*)d_in[13];
  const float* g2W = (const float*)d_in[14];
  const float* g2b = (const float*)d_in[15];
  const float* Wf  = (const float*)d_in[16];
  const float* bfp = (const float*)d_in[17];
  const float* Wc  = (const float*)d_in[18];
  const float* bcp = (const float*)d_in[19];
  const float* Wv  = (const float*)d_in[20];
  const float* bvp = (const float*)d_in[21];
  const float* Wa  = (const float*)d_in[22];
  const float* ba  = (const float*)d_in[23];
  const float* ls  = (const float*)d_in[24];
  float* out = (float*)d_out;
  float* w = (float*)d_ws;

  float* xT    = w;                 // 512*256
  float* xeT   = w + 131072;        // 1024*256
  float* hA    = w + 393216;        // 1024*256
  float* hB    = w + 655360;        // 1024*256
  float* commT = w + 917504;        // 1024*256
  float* psb   = w + 1179648;       // 256*512 (ps + b1, row-major)
  float* pdT   = w + 1310720;       // 512*256 (pd transposed)
  float* Wx    = w + 1441792;       // 256*1024 (row-major)
  float* AdjT  = w + 1703936;       // 256*256
  float* wd1   = w + 1769472;       // 512
  float* wd2   = w + 1769984;       // 512
  float* bd    = w + 1770496;       // 2

  prep_k<<<dim3(2),dim3(512),0,stream>>>(ha1W2, ha1b2, ha2W2, ha2b2, wd1, wd2, bd);
  transpose_k<<<dim3(16,8),dim3(32,8),0,stream>>>(x, xT);

  { // encoder: xeT = tanh(x@W_enc + b_enc), dual-store into hA (initial hidden)
    GCfg ce; ce.B=W_enc; ce.C=xeT; ce.bias=b_enc; ce.C2=hA; ce.ldb=HDIM; ce.ldc=N_AG; ce.ncols=HDIM; ce.flags=1|2|4|8;
    gemm_k<<<dim3(4,64,1),dim3(256),0,stream>>>(xT, NINP, ce, ce, ce);
  }

  for (int i=0;i<2;++i) {
    float* hIn  = i ? hB : hA;
    float* hOut = i ? hA : hB;
    { // fused: psb = h@W1a + b1 (row-major), pdT = (h@W1b)^T, Wx = h@g1W (row-major)
      GCfg c0; c0.B=ha1W1;          c0.C=psb; c0.bias=ha1b1;  c0.C2=nullptr; c0.ldb=512;  c0.ldc=512;  c0.ncols=512;  c0.flags=4;
      GCfg c1; c1.B=ha1W1+1024*512; c1.C=pdT; c1.bias=nullptr;c1.C2=nullptr; c1.ldb=512;  c1.ldc=N_AG; c1.ncols=512;  c1.flags=1;
      GCfg c2; c2.B=g1W;            c2.C=Wx;  c2.bias=nullptr;c2.C2=nullptr; c2.ldb=HDIM; c2.ldc=HDIM; c2.ncols=HDIM; c2.flags=0;
      gemm_k<<<dim3(4,64,3),dim3(256),0,stream>>>(hIn, HDIM, c0, c1, c2);
    }
    edge_k<<<dim3(128,2),dim3(256),0,stream>>>(psb, pdT, wd1, bd+0, gum + (size_t)(i*2+0)*EDG*2, AdjT);
    { // commT = ((Adj+I)@Wx + g1b)^T
      GCfg ca; ca.B=Wx; ca.C=commT; ca.bias=g1b; ca.C2=nullptr; ca.ldb=HDIM; ca.ldc=N_AG; ca.ncols=HDIM; ca.flags=1|4;
      gemm_k<<<dim3(4,64,1),dim3(256),0,stream>>>(AdjT, N_AG, ca, ca, ca);
    }
    { // fused on comm with ha2 / g2
      GCfg c0; c0.B=ha2W1;          c0.C=psb; c0.bias=ha2b1;  c0.C2=nullptr; c0.ldb=512;  c0.ldc=512;  c0.ncols=512;  c0.flags=4;
      GCfg c1; c1.B=ha2W1+1024*512; c1.C=pdT; c1.bias=nullptr;c1.C2=nullptr; c1.ldb=512;  c1.ldc=N_AG; c1.ncols=512;  c1.flags=1;
      GCfg c2; c2.B=g2W;            c2.C=Wx;  c2.bias=nullptr;c2.C2=nullptr; c2.ldb=HDIM; c2.ldc=HDIM; c2.ncols=HDIM; c2.flags=0;
      gemm_k<<<dim3(4,64,3),dim3(256),0,stream>>>(commT, HDIM, c0, c1, c2);
    }
    edge_k<<<dim3(128,2),dim3(256),0,stream>>>(psb, pdT, wd2, bd+1, gum + (size_t)(i*2+1)*EDG*2, AdjT);
    {
      GCfg ca; ca.B=Wx; ca.C=commT; ca.bias=g2b; ca.C2=nullptr; ca.ldb=HDIM; ca.ldc=N_AG; ca.ncols=HDIM; ca.flags=1|4;
      gemm_k<<<dim3(4,64,1),dim3(256),0,stream>>>(AdjT, N_AG, ca, ca, ca);
    }
    combine_k<<<dim3(4,64),dim3(256),0,stream>>>(hIn, Wf + (size_t)i*HDIM*HDIM, commT, Wc + (size_t)i*HDIM*HDIM,
                                                 xeT, bfp + i*HDIM, bcp + i*HDIM, hOut);
  }

  outinit_k<<<dim3(25),dim3(256),0,stream>>>(out, ba, ls, bvp);
  outpart_k<<<dim3(4,16),dim3(64),0,stream>>>(hA, Wa, Wv, out);
}

// Round 5
// 436.072 us; speedup vs baseline: 2.0834x; 2.0834x over previous
//
#include <hip/hip_runtime.h>

#define N_AG 256
#define HDIM 1024
#define NINP 512
#define EDG  65280

// ---- core: 8-col accumulate over a K-chunk. A is [K][256] k-major, B is [K][ldb] row-major.
__device__ __forceinline__ void gcore8(const float* __restrict__ Ap, const float* __restrict__ Bp,
                                       int kIters, int ldb, float acc[8]) {
  #pragma unroll 8
  for (int k=0; k<kIters; ++k) {
    float av = Ap[(size_t)k*N_AG];
    float4 b0 = *reinterpret_cast<const float4*>(Bp + (size_t)k*ldb);
    float4 b1 = *reinterpret_cast<const float4*>(Bp + (size_t)k*ldb + 4);
    acc[0]=fmaf(av,b0.x,acc[0]); acc[1]=fmaf(av,b0.y,acc[1]);
    acc[2]=fmaf(av,b0.z,acc[2]); acc[3]=fmaf(av,b0.w,acc[3]);
    acc[4]=fmaf(av,b1.x,acc[4]); acc[5]=fmaf(av,b1.y,acc[5]);
    acc[6]=fmaf(av,b1.z,acc[6]); acc[7]=fmaf(av,b1.w,acc[7]);
  }
}

// ---- cross-wave reduce: 4 waves hold partials of the same 64m x 8n tile.
// Thread -> (m_local = tid&63, col pair np = tid>>6).
__device__ __forceinline__ float2 kred(const float acc[8], int lane, int wv, int tid) {
  __shared__ float red[4][64][9];           // pad 9 to break bank conflicts
  #pragma unroll
  for (int j=0;j<8;++j) red[wv][lane][j] = acc[j];
  __syncthreads();
  int m = tid & 63, np = tid >> 6;
  float v0 = red[0][m][2*np]   + red[1][m][2*np]   + red[2][m][2*np]   + red[3][m][2*np];
  float v1 = red[0][m][2*np+1] + red[1][m][2*np+1] + red[2][m][2*np+1] + red[3][m][2*np+1];
  return make_float2(v0, v1);
}

// wd[k] = W2[k][1]-W2[k][0]; bd = b2[1]-b2[0]
__global__ __launch_bounds__(512) void prep_k(const float* w2a, const float* b2a,
                                              const float* w2b, const float* b2b,
                                              float* wd1, float* wd2, float* bd) {
  int z = blockIdx.x;
  const float* W2 = z ? w2b : w2a;
  float* wd = z ? wd2 : wd1;
  int t = threadIdx.x;
  if (t < 512) wd[t] = W2[2*t+1] - W2[2*t];
  if (t == 0) { const float* b2 = z ? b2b : b2a; bd[z] = b2[1] - b2[0]; }
}

// x [256][512] -> xT [512][256]
__global__ __launch_bounds__(256) void transpose_k(const float* __restrict__ x, float* __restrict__ xT) {
  __shared__ float tile[32][33];
  int tx = threadIdx.x, ty = threadIdx.y;
  int k0 = blockIdx.x*32, m0 = blockIdx.y*32;
  #pragma unroll
  for (int i=0;i<4;++i) tile[ty*4+i][tx] = x[(size_t)(m0+ty*4+i)*NINP + k0+tx];
  __syncthreads();
  #pragma unroll
  for (int i=0;i<4;++i) xT[(size_t)(k0+ty*4+i)*N_AG + m0+tx] = tile[tx][ty*4+i];
}

// encoder: xeT[n][m] = tanh(sum_k xT[k][m]*W_enc[k][n] + b_enc[n]); dual-store to hA
// grid (4, 128), block 256. K=512, wave chunk 128.
__global__ __launch_bounds__(256) void enc_k(const float* __restrict__ xT, const float* __restrict__ W,
                                             const float* __restrict__ b, float* __restrict__ xeT,
                                             float* __restrict__ hA) {
  int tid = threadIdx.x, lane = tid & 63;
  int wv = __builtin_amdgcn_readfirstlane(tid >> 6);
  int m  = blockIdx.x*64 + lane;
  int n0 = blockIdx.y*8;
  float acc[8] = {0,0,0,0,0,0,0,0};
  gcore8(xT + (size_t)(wv*128)*N_AG + m, W + (size_t)(wv*128)*HDIM + n0, 128, HDIM, acc);
  float2 v = kred(acc, lane, wv, tid);
  int mo = blockIdx.x*64 + (tid & 63), np = tid >> 6;   // FIX: block offset in store row
  int n  = n0 + 2*np;
  float t0 = tanhf(v.x + b[n]), t1 = tanhf(v.y + b[n+1]);
  xeT[(size_t)n*N_AG + mo] = t0; xeT[(size_t)(n+1)*N_AG + mo] = t1;
  hA [(size_t)n*N_AG + mo] = t0; hA [(size_t)(n+1)*N_AG + mo] = t1;
}

// fused: psb[s][j]=h@W1a+b1 (row), pdT[j][d]=(h@W1b)^T (colT), Wx[s][n]=h@gW (row)
// grid (4, 256): y<64 -> psb, y<128 -> pdT, else Wx. K=1024, wave chunk 256.
__global__ __launch_bounds__(256) void fused_k(const float* __restrict__ hT,
    const float* __restrict__ W1a, const float* __restrict__ W1b, const float* __restrict__ b1,
    const float* __restrict__ gW, float* __restrict__ psb, float* __restrict__ pdT,
    float* __restrict__ Wx) {
  int tid = threadIdx.x, lane = tid & 63;
  int wv = __builtin_amdgcn_readfirstlane(tid >> 6);
  int m  = blockIdx.x*64 + lane;
  int by = blockIdx.y;
  const float* B; int ldb, n0, mode; // mode 0: psb row+bias, 1: pdT colT, 2: Wx row
  if (by < 64)       { B = W1a; ldb = 512;  n0 = by*8;       mode = 0; }
  else if (by < 128) { B = W1b; ldb = 512;  n0 = (by-64)*8;  mode = 1; }
  else               { B = gW;  ldb = HDIM; n0 = (by-128)*8; mode = 2; }
  float acc[8] = {0,0,0,0,0,0,0,0};
  gcore8(hT + (size_t)(wv*256)*N_AG + m, B + (size_t)(wv*256)*ldb + n0, 256, ldb, acc);
  float2 v = kred(acc, lane, wv, tid);
  int mo = blockIdx.x*64 + (tid & 63), np = tid >> 6;   // FIX: block offset in store row
  int n  = n0 + 2*np;
  if (mode == 0) {
    psb[(size_t)mo*512 + n] = v.x + b1[n]; psb[(size_t)mo*512 + n+1] = v.y + b1[n+1];
  } else if (mode == 1) {
    pdT[(size_t)n*N_AG + mo] = v.x; pdT[(size_t)(n+1)*N_AG + mo] = v.y;
  } else {
    Wx[(size_t)mo*HDIM + n] = v.x; Wx[(size_t)mo*HDIM + n+1] = v.y;
  }
}

// AdjT[s][d] over 64-d group; 4 waves k-split 128 of the 512-dot.
// grid (4 dgroup, 256 s), block 256.
__global__ __launch_bounds__(256) void edge2_k(const float* __restrict__ psb,
    const float* __restrict__ pdT, const float* __restrict__ wd,
    const float* __restrict__ bdp, const float* __restrict__ g, float* __restrict__ AdjT) {
  __shared__ float red[4][65];
  int tid = threadIdx.x, lane = tid & 63;
  int wv = __builtin_amdgcn_readfirstlane(tid >> 6);
  int d  = blockIdx.x*64 + lane;
  int s  = blockIdx.y;
  const float* __restrict__ ps = psb + (size_t)s*512 + wv*128;
  const float* __restrict__ wp = wd + wv*128;
  const float* __restrict__ pp = pdT + (size_t)(wv*128)*N_AG + d;
  float acc = 0.f;
  #pragma unroll 8
  for (int k=0;k<128;++k)
    acc = fmaf(fmaxf(ps[k] + pp[(size_t)k*N_AG], 0.f), wp[k], acc);
  red[wv][lane] = acc;
  __syncthreads();
  if (wv == 0) {
    float tot = red[0][lane] + red[1][lane] + red[2][lane] + red[3][lane];
    int e = (d==s) ? 0 : (s*255 + d - (d>s ? 1 : 0));
    float g0 = g[2*e], g1 = g[2*e+1];
    float val = (tot + bdp[0] + g1 - g0) > 0.f ? 1.f : 0.f;
    if (d==s) val = 1.f;
    AdjT[(size_t)s*N_AG + d] = val;
  }
}

// commT[n][t] = sum_s AdjT[s][t]*Wx[s][n] + gb[n]. grid (4, 128). K=256, wave chunk 64.
__global__ __launch_bounds__(256) void adj_k(const float* __restrict__ AdjT, const float* __restrict__ Wx,
                                             const float* __restrict__ gb, float* __restrict__ commT) {
  int tid = threadIdx.x, lane = tid & 63;
  int wv = __builtin_amdgcn_readfirstlane(tid >> 6);
  int m  = blockIdx.x*64 + lane;
  int n0 = blockIdx.y*8;
  float acc[8] = {0,0,0,0,0,0,0,0};
  gcore8(AdjT + (size_t)(wv*64)*N_AG + m, Wx + (size_t)(wv*64)*HDIM + n0, 64, HDIM, acc);
  float2 v = kred(acc, lane, wv, tid);
  int mo = blockIdx.x*64 + (tid & 63), np = tid >> 6;   // FIX: block offset in store row
  int n  = n0 + 2*np;
  commT[(size_t)n*N_AG + mo] = v.x + gb[n];
  commT[(size_t)(n+1)*N_AG + mo] = v.y + gb[n+1];
}

// hOut = tanh(xeT + hT@Wf + cT@Wc + bf + bc), K=2048 concat; wave -> 512-chunk.
// grid (4, 128), block 256.
__global__ __launch_bounds__(256) void combine2_k(const float* __restrict__ hT, const float* __restrict__ cT,
    const float* __restrict__ Wf, const float* __restrict__ Wc, const float* __restrict__ xeT,
    const float* __restrict__ bfp, const float* __restrict__ bcp, float* __restrict__ hOut) {
  int tid = threadIdx.x, lane = tid & 63;
  int wv = __builtin_amdgcn_readfirstlane(tid >> 6);
  int m  = blockIdx.x*64 + lane;
  int n0 = blockIdx.y*8;
  int sel = wv >> 1, kb = (wv & 1)*512;
  const float* A = (sel ? cT : hT) + (size_t)kb*N_AG + m;
  const float* B = (sel ? Wc : Wf) + (size_t)kb*HDIM + n0;
  float acc[8] = {0,0,0,0,0,0,0,0};
  gcore8(A, B, 512, HDIM, acc);
  float2 v = kred(acc, lane, wv, tid);
  int mo = blockIdx.x*64 + (tid & 63), np = tid >> 6;   // FIX: block offset in store row
  int n  = n0 + 2*np;
  float r0 = v.x + xeT[(size_t)n*N_AG+mo]     + bfp[n]   + bcp[n];
  float r1 = v.y + xeT[(size_t)(n+1)*N_AG+mo] + bfp[n+1] + bcp[n+1];
  hOut[(size_t)n*N_AG + mo] = tanhf(r0);
  hOut[(size_t)(n+1)*N_AG + mo] = tanhf(r1);
}

// out init: a_mean=ba, a_log_std=ls, std=exp(ls), value=bv
__global__ __launch_bounds__(256) void outinit_k(float* out, const float* ba, const float* ls, const float* bvp) {
  int t = blockIdx.x*256 + threadIdx.x;
  if (t < 2048) out[t] = ba[t & 7];
  else if (t < 4096) out[t] = ls[t & 7];
  else if (t < 6144) out[t] = expf(ls[t & 7]);
  else if (t < 6400) out[t] = bvp[0];
}

// partial dot over c-chunk: out[m*8+j] += sum hT[c][m]*Wa[c][j]; out[6144+m] += sum hT[c][m]*Wv[c]
__global__ __launch_bounds__(64) void outpart_k(const float* __restrict__ hT, const float* __restrict__ Wa,
                                                const float* __restrict__ Wv, float* out) {
  int m = blockIdx.x*64 + threadIdx.x;
  int c0 = blockIdx.y*64;
  float acc[8] = {0,0,0,0,0,0,0,0};
  float av = 0.f;
  for (int c=c0; c<c0+64; ++c) {
    float h = hT[(size_t)c*N_AG + m];
    const float* wa = Wa + (size_t)c*8;
    #pragma unroll
    for (int j=0;j<8;++j) acc[j] = fmaf(h, wa[j], acc[j]);
    av = fmaf(h, Wv[c], av);
  }
  #pragma unroll
  for (int j=0;j<8;++j) atomicAdd(&out[m*8+j], acc[j]);
  atomicAdd(&out[6144+m], av);
}

extern "C" void kernel_launch(void* const* d_in, const int* in_sizes, int n_in,
                              void* d_out, int out_size, void* d_ws, size_t ws_size,
                              hipStream_t stream) {
  const float* x     = (const float*)d_in[0];
  const float* gum   = (const float*)d_in[1];
  const float* W_enc = (const float*)d_in[2];
  const float* b_enc = (const float*)d_in[3];
  const float* ha1W1 = (const float*)d_in[4];
  const float* ha1b1 = (const float*)d_in[5];
  const float* ha1W2 = (const float*)d_in[6];
  const float* ha1b2 = (const float*)d_in[7];
  const float* ha2W1 = (const float*)d_in[8];
  const float* ha2b1 = (const float*)d_in[9];
  const float* ha2W2 = (const float*)d_in[10];
  const float* ha2b2 = (const float*)d_in[11];
  const float* g1W = (const float*)d_in[12];
  const float* g1b = (const float*)d_in[13];
  const float* g2W = (const float*)d_in[14];
  const float* g2b = (const float*)d_in[15];
  const float* Wf  = (const float*)d_in[16];
  const float* bfp = (const float*)d_in[17];
  const float* Wc  = (const float*)d_in[18];
  const float* bcp = (const float*)d_in[19];
  const float* Wv  = (const float*)d_in[20];
  const float* bvp = (const float*)d_in[21];
  const float* Wa  = (const float*)d_in[22];
  const float* ba  = (const float*)d_in[23];
  const float* ls  = (const float*)d_in[24];
  float* out = (float*)d_out;
  float* w = (float*)d_ws;

  float* xT    = w;                 // 512*256
  float* xeT   = w + 131072;        // 1024*256
  float* hA    = w + 393216;        // 1024*256
  float* hB    = w + 655360;        // 1024*256
  float* commT = w + 917504;        // 1024*256
  float* psb   = w + 1179648;       // 256*512 row-major (incl. b1)
  float* pdT   = w + 1310720;       // 512*256 colT
  float* Wx    = w + 1441792;       // 256*1024 row-major
  float* AdjT  = w + 1703936;       // 256*256
  float* wd1   = w + 1769472;       // 512
  float* wd2   = w + 1769984;       // 512
  float* bd    = w + 1770496;       // 2

  prep_k<<<dim3(2),dim3(512),0,stream>>>(ha1W2, ha1b2, ha2W2, ha2b2, wd1, wd2, bd);
  transpose_k<<<dim3(16,8),dim3(32,8),0,stream>>>(x, xT);
  enc_k<<<dim3(4,128),dim3(256),0,stream>>>(xT, W_enc, b_enc, xeT, hA);

  for (int i=0;i<2;++i) {
    float* hIn  = i ? hB : hA;
    float* hOut = i ? hA : hB;

    fused_k<<<dim3(4,256),dim3(256),0,stream>>>(hIn, ha1W1, ha1W1 + 1024*512, ha1b1, g1W, psb, pdT, Wx);
    edge2_k<<<dim3(4,256),dim3(256),0,stream>>>(psb, pdT, wd1, bd+0, gum + (size_t)(i*2+0)*EDG*2, AdjT);
    adj_k<<<dim3(4,128),dim3(256),0,stream>>>(AdjT, Wx, g1b, commT);

    fused_k<<<dim3(4,256),dim3(256),0,stream>>>(commT, ha2W1, ha2W1 + 1024*512, ha2b1, g2W, psb, pdT, Wx);
    edge2_k<<<dim3(4,256),dim3(256),0,stream>>>(psb, pdT, wd2, bd+1, gum + (size_t)(i*2+1)*EDG*2, AdjT);
    adj_k<<<dim3(4,128),dim3(256),0,stream>>>(AdjT, Wx, g2b, commT);

    combine2_k<<<dim3(4,128),dim3(256),0,stream>>>(hIn, commT, Wf + (size_t)i*HDIM*HDIM, Wc + (size_t)i*HDIM*HDIM,
                                                   xeT, bfp + i*HDIM, bcp + i*HDIM, hOut);
  }

  outinit_k<<<dim3(25),dim3(256),0,stream>>>(out, ba, ls, bvp);
  outpart_k<<<dim3(4,16),dim3(64),0,stream>>>(hA, Wa, Wv, out);
}

// Round 7
// 382.558 us; speedup vs baseline: 2.3748x; 1.1399x over previous
//
#include <hip/hip_runtime.h>

#define N_AG 256
#define HDIM 1024
#define NINP 512
#define EDG  65280

// XCD-aware bijective swizzle: linear blocks round-robin XCDs (b%8), remap so each
// XCD owns a contiguous id range. Requires nw % 8 == 0.
__device__ __forceinline__ int swz8(int b, int nw) {
  return (b & 7) * (nw >> 3) + (b >> 3);
}

// ---- core: 8-col accumulate over a K-chunk. A is [K][256] k-major, B is [K][ldb] row-major.
__device__ __forceinline__ void gcore8(const float* __restrict__ Ap, const float* __restrict__ Bp,
                                       int kIters, int ldb, float acc[8]) {
  #pragma unroll 8
  for (int k=0; k<kIters; ++k) {
    float av = Ap[(size_t)k*N_AG];
    float4 b0 = *reinterpret_cast<const float4*>(Bp + (size_t)k*ldb);
    float4 b1 = *reinterpret_cast<const float4*>(Bp + (size_t)k*ldb + 4);
    acc[0]=fmaf(av,b0.x,acc[0]); acc[1]=fmaf(av,b0.y,acc[1]);
    acc[2]=fmaf(av,b0.z,acc[2]); acc[3]=fmaf(av,b0.w,acc[3]);
    acc[4]=fmaf(av,b1.x,acc[4]); acc[5]=fmaf(av,b1.y,acc[5]);
    acc[6]=fmaf(av,b1.z,acc[6]); acc[7]=fmaf(av,b1.w,acc[7]);
  }
}

// ---- cross-wave reduce: 8 waves hold partials of the same 64m x 8n tile.
// Thread t -> one output (m = t&63, n-offset j = t>>6). Stride-9 pad: conflict-free.
__device__ __forceinline__ float kred8(const float acc[8], int lane, int wv, int tid) {
  __shared__ float red[8][64][9];
  #pragma unroll
  for (int j=0;j<8;++j) red[wv][lane][j] = acc[j];
  __syncthreads();
  int m = tid & 63, j = tid >> 6;
  float v = 0.f;
  #pragma unroll
  for (int w=0;w<8;++w) v += red[w][m][j];
  return v;
}

// wd[k] = W2[k][1]-W2[k][0]; bd = b2[1]-b2[0]
__global__ __launch_bounds__(512) void prep_k(const float* w2a, const float* b2a,
                                              const float* w2b, const float* b2b,
                                              float* wd1, float* wd2, float* bd) {
  int z = blockIdx.x;
  const float* W2 = z ? w2b : w2a;
  float* wd = z ? wd2 : wd1;
  int t = threadIdx.x;
  if (t < 512) wd[t] = W2[2*t+1] - W2[2*t];
  if (t == 0) { const float* b2 = z ? b2b : b2a; bd[z] = b2[1] - b2[0]; }
}

// x [256][512] -> xT [512][256]
__global__ __launch_bounds__(256) void transpose_k(const float* __restrict__ x, float* __restrict__ xT) {
  __shared__ float tile[32][33];
  int tx = threadIdx.x, ty = threadIdx.y;
  int k0 = blockIdx.x*32, m0 = blockIdx.y*32;
  #pragma unroll
  for (int i=0;i<4;++i) tile[ty*4+i][tx] = x[(size_t)(m0+ty*4+i)*NINP + k0+tx];
  __syncthreads();
  #pragma unroll
  for (int i=0;i<4;++i) xT[(size_t)(k0+ty*4+i)*N_AG + m0+tx] = tile[tx][ty*4+i];
}

// encoder: xeT[n][m] = tanh(sum_k xT[k][m]*W_enc[k][n] + b_enc[n]); dual-store to hA
// 512 blocks x 512 thr. K=512, wave chunk 64.
__global__ __launch_bounds__(512) void enc_k(const float* __restrict__ xT, const float* __restrict__ W,
                                             const float* __restrict__ b, float* __restrict__ xeT,
                                             float* __restrict__ hA) {
  int tid = threadIdx.x, lane = tid & 63;
  int wv = __builtin_amdgcn_readfirstlane(tid >> 6);
  int id = swz8(blockIdx.x, 512);
  int mb = id & 3, n0 = (id >> 2) * 8;
  int m  = mb*64 + lane;
  float acc[8] = {0,0,0,0,0,0,0,0};
  gcore8(xT + (size_t)(wv*64)*N_AG + m, W + (size_t)(wv*64)*HDIM + n0, 64, HDIM, acc);
  float v = kred8(acc, lane, wv, tid);
  int mo = mb*64 + (tid & 63);
  int n  = n0 + (tid >> 6);
  float t0 = tanhf(v + b[n]);
  xeT[(size_t)n*N_AG + mo] = t0;
  hA [(size_t)n*N_AG + mo] = t0;
}

// fused: psT[j][s]=(h@W1a+b1)^T, pdT[j][d]=(h@W1b)^T, Wx[s][n]=h@gW (row)
// 1024 blocks x 512 thr. K=1024, wave chunk 128. by: 0-63 psT, 64-127 pdT, 128-255 Wx.
__global__ __launch_bounds__(512) void fused_k(const float* __restrict__ hT,
    const float* __restrict__ W1a, const float* __restrict__ W1b, const float* __restrict__ b1,
    const float* __restrict__ gW, float* __restrict__ psT, float* __restrict__ pdT,
    float* __restrict__ Wx) {
  int tid = threadIdx.x, lane = tid & 63;
  int wv = __builtin_amdgcn_readfirstlane(tid >> 6);
  int id = swz8(blockIdx.x, 1024);
  int mb = id & 3, by = id >> 2;
  const float* B; int ldb, n0, mode;
  if (by < 64)       { B = W1a; ldb = 512;  n0 = by*8;       mode = 0; }
  else if (by < 128) { B = W1b; ldb = 512;  n0 = (by-64)*8;  mode = 1; }
  else               { B = gW;  ldb = HDIM; n0 = (by-128)*8; mode = 2; }
  int m = mb*64 + lane;
  float acc[8] = {0,0,0,0,0,0,0,0};
  gcore8(hT + (size_t)(wv*128)*N_AG + m, B + (size_t)(wv*128)*ldb + n0, 128, ldb, acc);
  float v = kred8(acc, lane, wv, tid);
  int mo = mb*64 + (tid & 63);
  int n  = n0 + (tid >> 6);
  if (mode == 0)      psT[(size_t)n*N_AG + mo] = v + b1[n];
  else if (mode == 1) pdT[(size_t)n*N_AG + mo] = v;
  else                Wx [(size_t)mo*HDIM + n] = v;
}

// AdjT[s][d]: 4 waves k-split 128 of the 512-dot. psT reads wave-uniform -> scalar.
// grid (4 dgroup, 256 s), block 256.
__global__ __launch_bounds__(256) void edge2_k(const float* __restrict__ psT,
    const float* __restrict__ pdT, const float* __restrict__ wd,
    const float* __restrict__ bdp, const float* __restrict__ g, float* __restrict__ AdjT) {
  __shared__ float red[4][65];
  int tid = threadIdx.x, lane = tid & 63;
  int wv = __builtin_amdgcn_readfirstlane(tid >> 6);
  int d  = blockIdx.x*64 + lane;
  int s  = blockIdx.y;
  const float* __restrict__ ps = psT + (size_t)(wv*128)*N_AG + s;   // psT[k][s]
  const float* __restrict__ wp = wd + wv*128;
  const float* __restrict__ pp = pdT + (size_t)(wv*128)*N_AG + d;
  float acc = 0.f;
  #pragma unroll 8
  for (int k=0;k<128;++k)
    acc = fmaf(fmaxf(ps[(size_t)k*N_AG] + pp[(size_t)k*N_AG], 0.f), wp[k], acc);
  red[wv][lane] = acc;
  __syncthreads();
  if (wv == 0) {
    float tot = red[0][lane] + red[1][lane] + red[2][lane] + red[3][lane];
    int e = (d==s) ? 0 : (s*255 + d - (d>s ? 1 : 0));
    float g0 = g[2*e], g1 = g[2*e+1];
    float val = (tot + bdp[0] + g1 - g0) > 0.f ? 1.f : 0.f;
    if (d==s) val = 1.f;
    AdjT[(size_t)s*N_AG + d] = val;
  }
}

// commT[n][t] = sum_s AdjT[s][t]*Wx[s][n] + gb[n]. 512 blocks x 512 thr. K=256, wave chunk 32.
__global__ __launch_bounds__(512) void adj_k(const float* __restrict__ AdjT, const float* __restrict__ Wx,
                                             const float* __restrict__ gb, float* __restrict__ commT) {
  int tid = threadIdx.x, lane = tid & 63;
  int wv = __builtin_amdgcn_readfirstlane(tid >> 6);
  int id = swz8(blockIdx.x, 512);
  int mb = id & 3, n0 = (id >> 2) * 8;
  int m  = mb*64 + lane;
  float acc[8] = {0,0,0,0,0,0,0,0};
  gcore8(AdjT + (size_t)(wv*32)*N_AG + m, Wx + (size_t)(wv*32)*HDIM + n0, 32, HDIM, acc);
  float v = kred8(acc, lane, wv, tid);
  int mo = mb*64 + (tid & 63);
  int n  = n0 + (tid >> 6);
  commT[(size_t)n*N_AG + mo] = v + gb[n];
}

// hOut = tanh(xeT + hT@Wf + cT@Wc + bf + bc). 512 blocks x 512 thr.
// waves 0-3: hT@Wf (k-chunks of 256); waves 4-7: cT@Wc.
__global__ __launch_bounds__(512) void combine2_k(const float* __restrict__ hT, const float* __restrict__ cT,
    const float* __restrict__ Wf, const float* __restrict__ Wc, const float* __restrict__ xeT,
    const float* __restrict__ bfp, const float* __restrict__ bcp, float* __restrict__ hOut) {
  int tid = threadIdx.x, lane = tid & 63;
  int wv = __builtin_amdgcn_readfirstlane(tid >> 6);
  int id = swz8(blockIdx.x, 512);
  int mb = id & 3, n0 = (id >> 2) * 8;
  int m  = mb*64 + lane;
  int sel = wv >> 2, kb = (wv & 3)*256;
  const float* A = (sel ? cT : hT) + (size_t)kb*N_AG + m;
  const float* B = (sel ? Wc : Wf) + (size_t)kb*HDIM + n0;
  float acc[8] = {0,0,0,0,0,0,0,0};
  gcore8(A, B, 256, HDIM, acc);
  float v = kred8(acc, lane, wv, tid);
  int mo = mb*64 + (tid & 63);
  int n  = n0 + (tid >> 6);
  float r = v + xeT[(size_t)n*N_AG + mo] + bfp[n] + bcp[n];
  hOut[(size_t)n*N_AG + mo] = tanhf(r);
}

// out init: a_mean=ba, a_log_std=ls, std=exp(ls), value=bv
__global__ __launch_bounds__(256) void outinit_k(float* out, const float* ba, const float* ls, const float* bvp) {
  int t = blockIdx.x*256 + threadIdx.x;
  if (t < 2048) out[t] = ba[t & 7];
  else if (t < 4096) out[t] = ls[t & 7];
  else if (t < 6144) out[t] = expf(ls[t & 7]);
  else if (t < 6400) out[t] = bvp[0];
}

// partial dot over c-chunk: out[m*8+j] += sum hT[c][m]*Wa[c][j]; out[6144+m] += sum hT[c][m]*Wv[c]
__global__ __launch_bounds__(64) void outpart_k(const float* __restrict__ hT, const float* __restrict__ Wa,
                                                const float* __restrict__ Wv, float* out) {
  int m = blockIdx.x*64 + threadIdx.x;
  int c0 = blockIdx.y*64;
  float acc[8] = {0,0,0,0,0,0,0,0};
  float av = 0.f;
  for (int c=c0; c<c0+64; ++c) {
    float h = hT[(size_t)c*N_AG + m];
    const float* wa = Wa + (size_t)c*8;
    #pragma unroll
    for (int j=0;j<8;++j) acc[j] = fmaf(h, wa[j], acc[j]);
    av = fmaf(h, Wv[c], av);
  }
  #pragma unroll
  for (int j=0;j<8;++j) atomicAdd(&out[m*8+j], acc[j]);
  atomicAdd(&out[6144+m], av);
}

extern "C" void kernel_launch(void* const* d_in, const int* in_sizes, int n_in,
                              void* d_out, int out_size, void* d_ws, size_t ws_size,
                              hipStream_t stream) {
  const float* x     = (const float*)d_in[0];
  const float* gum   = (const float*)d_in[1];
  const float* W_enc = (const float*)d_in[2];
  const float* b_enc = (const float*)d_in[3];
  const float* ha1W1 = (const float*)d_in[4];
  const float* ha1b1 = (const float*)d_in[5];
  const float* ha1W2 = (const float*)d_in[6];
  const float* ha1b2 = (const float*)d_in[7];
  const float* ha2W1 = (const float*)d_in[8];
  const float* ha2b1 = (const float*)d_in[9];
  const float* ha2W2 = (const float*)d_in[10];
  const float* ha2b2 = (const float*)d_in[11];
  const float* g1W = (const float*)d_in[12];
  const float* g1b = (const float*)d_in[13];
  const float* g2W = (const float*)d_in[14];
  const float* g2b = (const float*)d_in[15];
  const float* Wf  = (const float*)d_in[16];
  const float* bfp = (const float*)d_in[17];
  const float* Wc  = (const float*)d_in[18];
  const float* bcp = (const float*)d_in[19];
  const float* Wv  = (const float*)d_in[20];
  const float* bvp = (const float*)d_in[21];
  const float* Wa  = (const float*)d_in[22];
  const float* ba  = (const float*)d_in[23];
  const float* ls  = (const float*)d_in[24];
  float* out = (float*)d_out;
  float* w = (float*)d_ws;

  float* xT    = w;                 // 512*256
  float* xeT   = w + 131072;        // 1024*256
  float* hA    = w + 393216;        // 1024*256
  float* hB    = w + 655360;        // 1024*256
  float* commT = w + 917504;        // 1024*256
  float* psT   = w + 1179648;       // 512*256 colT (incl. b1)
  float* pdT   = w + 1310720;       // 512*256 colT
  float* Wx    = w + 1441792;       // 256*1024 row-major
  float* AdjT  = w + 1703936;       // 256*256
  float* wd1   = w + 1769472;       // 512
  float* wd2   = w + 1769984;       // 512
  float* bd    = w + 1770496;       // 2

  prep_k<<<dim3(2),dim3(512),0,stream>>>(ha1W2, ha1b2, ha2W2, ha2b2, wd1, wd2, bd);
  transpose_k<<<dim3(16,8),dim3(32,8),0,stream>>>(x, xT);
  enc_k<<<dim3(512),dim3(512),0,stream>>>(xT, W_enc, b_enc, xeT, hA);

  for (int i=0;i<2;++i) {
    float* hIn  = i ? hB : hA;
    float* hOut = i ? hA : hB;

    fused_k<<<dim3(1024),dim3(512),0,stream>>>(hIn, ha1W1, ha1W1 + 1024*512, ha1b1, g1W, psT, pdT, Wx);
    edge2_k<<<dim3(4,256),dim3(256),0,stream>>>(psT, pdT, wd1, bd+0, gum + (size_t)(i*2+0)*EDG*2, AdjT);
    adj_k<<<dim3(512),dim3(512),0,stream>>>(AdjT, Wx, g1b, commT);

    fused_k<<<dim3(1024),dim3(512),0,stream>>>(commT, ha2W1, ha2W1 + 1024*512, ha2b1, g2W, psT, pdT, Wx);
    edge2_k<<<dim3(4,256),dim3(256),0,stream>>>(psT, pdT, wd2, bd+1, gum + (size_t)(i*2+1)*EDG*2, AdjT);
    adj_k<<<dim3(512),dim3(512),0,stream>>>(AdjT, Wx, g2b, commT);

    combine2_k<<<dim3(512),dim3(512),0,stream>>>(hIn, commT, Wf + (size_t)i*HDIM*HDIM, Wc + (size_t)i*HDIM*HDIM,
                                                 xeT, bfp + i*HDIM, bcp + i*HDIM, hOut);
  }

  outinit_k<<<dim3(25),dim3(256),0,stream>>>(out, ba, ls, bvp);
  outpart_k<<<dim3(4,16),dim3(64),0,stream>>>(hA, Wa, Wv, out);
}

// Round 9
// 365.114 us; speedup vs baseline: 2.4883x; 1.0478x over previous
//
#include <hip/hip_runtime.h>

#define N_AG 256
#define HDIM 1024
#define NINP 512
#define EDG  65280

// XCD-aware bijective swizzle: linear blocks round-robin XCDs (b%8), remap so each
// XCD owns a contiguous id range. Requires nw % 8 == 0.
__device__ __forceinline__ int swz8(int b, int nw) {
  return (b & 7) * (nw >> 3) + (b >> 3);
}

#define FMA8(av, B0, B1) \
  acc[0]=fmaf(av,B0.x,acc[0]); acc[1]=fmaf(av,B0.y,acc[1]); \
  acc[2]=fmaf(av,B0.z,acc[2]); acc[3]=fmaf(av,B0.w,acc[3]); \
  acc[4]=fmaf(av,B1.x,acc[4]); acc[5]=fmaf(av,B1.y,acc[5]); \
  acc[6]=fmaf(av,B1.z,acc[6]); acc[7]=fmaf(av,B1.w,acc[7]);

// ---- core: 8-col accumulate over a K-chunk, register double-buffered.
// A is [K][256] k-major, B is [K][LDB] row-major. FMA order: k ascending,
// cols 0..7 per k — bit-identical to the round-7 kernel.
template<int LDB>
__device__ __forceinline__ void gcore8(const float* __restrict__ Ap, const float* __restrict__ Bp,
                                       int kIters, float acc[8]) {
  float a0 = Ap[0];
  float a1 = Ap[N_AG];
  float4 p0 = *reinterpret_cast<const float4*>(Bp);
  float4 p1 = *reinterpret_cast<const float4*>(Bp + 4);
  float4 q0 = *reinterpret_cast<const float4*>(Bp + LDB);
  float4 q1 = *reinterpret_cast<const float4*>(Bp + LDB + 4);
  #pragma unroll 2
  for (int k = 0; k < kIters - 2; k += 2) {
    // prefetch group k+2 BEFORE consuming group k
    float na0 = Ap[(size_t)(k+2)*N_AG];
    float na1 = Ap[(size_t)(k+3)*N_AG];
    float4 np0 = *reinterpret_cast<const float4*>(Bp + (size_t)(k+2)*LDB);
    float4 np1 = *reinterpret_cast<const float4*>(Bp + (size_t)(k+2)*LDB + 4);
    float4 nq0 = *reinterpret_cast<const float4*>(Bp + (size_t)(k+3)*LDB);
    float4 nq1 = *reinterpret_cast<const float4*>(Bp + (size_t)(k+3)*LDB + 4);
    FMA8(a0, p0, p1);
    FMA8(a1, q0, q1);
    a0 = na0; a1 = na1; p0 = np0; p1 = np1; q0 = nq0; q1 = nq1;
  }
  FMA8(a0, p0, p1);
  FMA8(a1, q0, q1);
}

// ---- cross-wave reduce: 8 waves hold partials of the same 64m x 8n tile.
// Thread t -> one output (m = t&63, n-offset j = t>>6). Stride-9 pad: conflict-free.
__device__ __forceinline__ float kred8(const float acc[8], int lane, int wv, int tid) {
  __shared__ float red[8][64][9];
  #pragma unroll
  for (int j=0;j<8;++j) red[wv][lane][j] = acc[j];
  __syncthreads();
  int m = tid & 63, j = tid >> 6;
  float v = 0.f;
  #pragma unroll
  for (int w=0;w<8;++w) v += red[w][m][j];
  return v;
}

// merged: blocks 0..127 transpose x; block 128: wd1+bd[0]; block 129: wd2+bd[1]
__global__ __launch_bounds__(256) void prepT_k(const float* __restrict__ x, float* __restrict__ xT,
                                               const float* w2a, const float* b2a,
                                               const float* w2b, const float* b2b,
                                               float* wd1, float* wd2, float* bd) {
  int bid = blockIdx.x;
  if (bid >= 128) {
    int z = bid - 128;
    const float* W2 = z ? w2b : w2a;
    float* wd = z ? wd2 : wd1;
    int t = threadIdx.x;
    wd[t]       = W2[2*t+1]       - W2[2*t];
    wd[t+256]   = W2[2*(t+256)+1] - W2[2*(t+256)];
    if (t == 0) { const float* b2 = z ? b2b : b2a; bd[z] = b2[1] - b2[0]; }
    return;
  }
  __shared__ float tile[32][33];
  int tx = threadIdx.x & 31, ty = threadIdx.x >> 5;
  int k0 = (bid & 15)*32, m0 = (bid >> 4)*32;
  #pragma unroll
  for (int i=0;i<4;++i) tile[ty*4+i][tx] = x[(size_t)(m0+ty*4+i)*NINP + k0+tx];
  __syncthreads();
  #pragma unroll
  for (int i=0;i<4;++i) xT[(size_t)(k0+ty*4+i)*N_AG + m0+tx] = tile[tx][ty*4+i];
}

// encoder: xeT[n][m] = tanh(sum_k xT[k][m]*W_enc[k][n] + b_enc[n]); dual-store to hA
// 512 blocks x 512 thr. K=512, wave chunk 64.
__global__ __launch_bounds__(512, 8) void enc_k(const float* __restrict__ xT, const float* __restrict__ W,
                                                const float* __restrict__ b, float* __restrict__ xeT,
                                                float* __restrict__ hA) {
  int tid = threadIdx.x, lane = tid & 63;
  int wv = __builtin_amdgcn_readfirstlane(tid >> 6);
  int id = swz8(blockIdx.x, 512);
  int mb = id & 3, n0 = (id >> 2) * 8;
  int m  = mb*64 + lane;
  float acc[8] = {0,0,0,0,0,0,0,0};
  gcore8<HDIM>(xT + (size_t)(wv*64)*N_AG + m, W + (size_t)(wv*64)*HDIM + n0, 64, acc);
  float v = kred8(acc, lane, wv, tid);
  int mo = mb*64 + (tid & 63);
  int n  = n0 + (tid >> 6);
  float t0 = tanhf(v + b[n]);
  xeT[(size_t)n*N_AG + mo] = t0;
  hA [(size_t)n*N_AG + mo] = t0;
}

// fused: psT[j][s]=(h@W1a+b1)^T, pdT[j][d]=(h@W1b)^T, Wx[s][n]=h@gW (row)
// 1024 blocks x 512 thr. K=1024, wave chunk 128. by: 0-63 psT, 64-127 pdT, 128-255 Wx.
__global__ __launch_bounds__(512, 8) void fused_k(const float* __restrict__ hT,
    const float* __restrict__ W1a, const float* __restrict__ W1b, const float* __restrict__ b1,
    const float* __restrict__ gW, float* __restrict__ psT, float* __restrict__ pdT,
    float* __restrict__ Wx) {
  int tid = threadIdx.x, lane = tid & 63;
  int wv = __builtin_amdgcn_readfirstlane(tid >> 6);
  int id = swz8(blockIdx.x, 1024);
  int mb = id & 3, by = id >> 2;
  int m = mb*64 + lane;
  float acc[8] = {0,0,0,0,0,0,0,0};
  int n0, mode;
  if (by < 64) {
    n0 = by*8; mode = 0;
    gcore8<512>(hT + (size_t)(wv*128)*N_AG + m, W1a + (size_t)(wv*128)*512 + n0, 128, acc);
  } else if (by < 128) {
    n0 = (by-64)*8; mode = 1;
    gcore8<512>(hT + (size_t)(wv*128)*N_AG + m, W1b + (size_t)(wv*128)*512 + n0, 128, acc);
  } else {
    n0 = (by-128)*8; mode = 2;
    gcore8<HDIM>(hT + (size_t)(wv*128)*N_AG + m, gW + (size_t)(wv*128)*HDIM + n0, 128, acc);
  }
  float v = kred8(acc, lane, wv, tid);
  int mo = mb*64 + (tid & 63);
  int n  = n0 + (tid >> 6);
  if (mode == 0)      psT[(size_t)n*N_AG + mo] = v + b1[n];
  else if (mode == 1) pdT[(size_t)n*N_AG + mo] = v;
  else                Wx [(size_t)mo*HDIM + n] = v;
}

// AdjT[s][d]: 4 waves k-split 128 of the 512-dot. UNCHANGED (numerics frozen).
// grid (4 dgroup, 256 s), block 256.
__global__ __launch_bounds__(256) void edge2_k(const float* __restrict__ psT,
    const float* __restrict__ pdT, const float* __restrict__ wd,
    const float* __restrict__ bdp, const float* __restrict__ g, float* __restrict__ AdjT) {
  __shared__ float red[4][65];
  int tid = threadIdx.x, lane = tid & 63;
  int wv = __builtin_amdgcn_readfirstlane(tid >> 6);
  int d  = blockIdx.x*64 + lane;
  int s  = blockIdx.y;
  const float* __restrict__ ps = psT + (size_t)(wv*128)*N_AG + s;   // psT[k][s]
  const float* __restrict__ wp = wd + wv*128;
  const float* __restrict__ pp = pdT + (size_t)(wv*128)*N_AG + d;
  float acc = 0.f;
  #pragma unroll 8
  for (int k=0;k<128;++k)
    acc = fmaf(fmaxf(ps[(size_t)k*N_AG] + pp[(size_t)k*N_AG], 0.f), wp[k], acc);
  red[wv][lane] = acc;
  __syncthreads();
  if (wv == 0) {
    float tot = red[0][lane] + red[1][lane] + red[2][lane] + red[3][lane];
    int e = (d==s) ? 0 : (s*255 + d - (d>s ? 1 : 0));
    float g0 = g[2*e], g1 = g[2*e+1];
    float val = (tot + bdp[0] + g1 - g0) > 0.f ? 1.f : 0.f;
    if (d==s) val = 1.f;
    AdjT[(size_t)s*N_AG + d] = val;
  }
}

// commT[n][t] = sum_s AdjT[s][t]*Wx[s][n] + gb[n]. 512 blocks x 512 thr. K=256, wave chunk 32.
__global__ __launch_bounds__(512, 8) void adj_k(const float* __restrict__ AdjT, const float* __restrict__ Wx,
                                                const float* __restrict__ gb, float* __restrict__ commT) {
  int tid = threadIdx.x, lane = tid & 63;
  int wv = __builtin_amdgcn_readfirstlane(tid >> 6);
  int id = swz8(blockIdx.x, 512);
  int mb = id & 3, n0 = (id >> 2) * 8;
  int m  = mb*64 + lane;
  float acc[8] = {0,0,0,0,0,0,0,0};
  gcore8<HDIM>(AdjT + (size_t)(wv*32)*N_AG + m, Wx + (size_t)(wv*32)*HDIM + n0, 32, acc);
  float v = kred8(acc, lane, wv, tid);
  int mo = mb*64 + (tid & 63);
  int n  = n0 + (tid >> 6);
  commT[(size_t)n*N_AG + mo] = v + gb[n];
}

// hOut = tanh(xeT + hT@Wf + cT@Wc + bf + bc). 512 blocks x 512 thr.
// waves 0-3: hT@Wf (k-chunks of 256); waves 4-7: cT@Wc.
__global__ __launch_bounds__(512, 8) void combine2_k(const float* __restrict__ hT, const float* __restrict__ cT,
    const float* __restrict__ Wf, const float* __restrict__ Wc, const float* __restrict__ xeT,
    const float* __restrict__ bfp, const float* __restrict__ bcp, float* __restrict__ hOut) {
  int tid = threadIdx.x, lane = tid & 63;
  int wv = __builtin_amdgcn_readfirstlane(tid >> 6);
  int id = swz8(blockIdx.x, 512);
  int mb = id & 3, n0 = (id >> 2) * 8;
  int m  = mb*64 + lane;
  int sel = wv >> 2, kb = (wv & 3)*256;
  const float* A = (sel ? cT : hT) + (size_t)kb*N_AG + m;
  const float* B = (sel ? Wc : Wf) + (size_t)kb*HDIM + n0;
  float acc[8] = {0,0,0,0,0,0,0,0};
  gcore8<HDIM>(A, B, 256, acc);
  float v = kred8(acc, lane, wv, tid);
  int mo = mb*64 + (tid & 63);
  int n  = n0 + (tid >> 6);
  float r = v + xeT[(size_t)n*N_AG + mo] + bfp[n] + bcp[n];
  hOut[(size_t)n*N_AG + mo] = tanhf(r);
}

// out init: a_mean=ba, a_log_std=ls, std=exp(ls), value=bv
__global__ __launch_bounds__(256) void outinit_k(float* out, const float* ba, const float* ls, const float* bvp) {
  int t = blockIdx.x*256 + threadIdx.x;
  if (t < 2048) out[t] = ba[t & 7];
  else if (t < 4096) out[t] = ls[t & 7];
  else if (t < 6144) out[t] = expf(ls[t & 7]);
  else if (t < 6400) out[t] = bvp[0];
}

// partial dot over c-chunk: out[m*8+j] += sum hT[c][m]*Wa[c][j]; out[6144+m] += sum hT[c][m]*Wv[c]
__global__ __launch_bounds__(64) void outpart_k(const float* __restrict__ hT, const float* __restrict__ Wa,
                                                const float* __restrict__ Wv, float* out) {
  int m = blockIdx.x*64 + threadIdx.x;
  int c0 = blockIdx.y*64;
  float acc[8] = {0,0,0,0,0,0,0,0};
  float av = 0.f;
  for (int c=c0; c<c0+64; ++c) {
    float h = hT[(size_t)c*N_AG + m];
    const float* wa = Wa + (size_t)c*8;
    #pragma unroll
    for (int j=0;j<8;++j) acc[j] = fmaf(h, wa[j], acc[j]);
    av = fmaf(h, Wv[c], av);
  }
  #pragma unroll
  for (int j=0;j<8;++j) atomicAdd(&out[m*8+j], acc[j]);
  atomicAdd(&out[6144+m], av);
}

extern "C" void kernel_launch(void* const* d_in, const int* in_sizes, int n_in,
                              void* d_out, int out_size, void* d_ws, size_t ws_size,
                              hipStream_t stream) {
  const float* x     = (const float*)d_in[0];
  const float* gum   = (const float*)d_in[1];
  const float* W_enc = (const float*)d_in[2];
  const float* b_enc = (const float*)d_in[3];
  const float* ha1W1 = (const float*)d_in[4];
  const float* ha1b1 = (const float*)d_in[5];
  const float* ha1W2 = (const float*)d_in[6];
  const float* ha1b2 = (const float*)d_in[7];
  const float* ha2W1 = (const float*)d_in[8];
  const float* ha2b1 = (const float*)d_in[9];
  const float* ha2W2 = (const float*)d_in[10];
  const float* ha2b2 = (const float*)d_in[11];
  const float* g1W = (const float*)d_in[12];
  const float* g1b = (const float*)d_in[13];
  const float* g2W = (const float*)d_in[14];
  const float* g2b = (const float*)d_in[15];
  const float* Wf  = (const float*)d_in[16];
  const float* bfp = (const float*)d_in[17];
  const float* Wc  = (const float*)d_in[18];
  const float* bcp = (const float*)d_in[19];
  const float* Wv  = (const float*)d_in[20];
  const float* bvp = (const float*)d_in[21];
  const float* Wa  = (const float*)d_in[22];
  const float* ba  = (const float*)d_in[23];
  const float* ls  = (const float*)d_in[24];
  float* out = (float*)d_out;
  float* w = (float*)d_ws;

  float* xT    = w;                 // 512*256
  float* xeT   = w + 131072;        // 1024*256
  float* hA    = w + 393216;        // 1024*256
  float* hB    = w + 655360;        // 1024*256
  float* commT = w + 917504;        // 1024*256
  float* psT   = w + 1179648;       // 512*256 colT (incl. b1)
  float* pdT   = w + 1310720;       // 512*256 colT
  float* Wx    = w + 1441792;       // 256*1024 row-major
  float* AdjT  = w + 1703936;       // 256*256
  float* wd1   = w + 1769472;       // 512
  float* wd2   = w + 1769984;       // 512
  float* bd    = w + 1770496;       // 2

  prepT_k<<<dim3(130),dim3(256),0,stream>>>(x, xT, ha1W2, ha1b2, ha2W2, ha2b2, wd1, wd2, bd);
  enc_k<<<dim3(512),dim3(512),0,stream>>>(xT, W_enc, b_enc, xeT, hA);

  for (int i=0;i<2;++i) {
    float* hIn  = i ? hB : hA;
    float* hOut = i ? hA : hB;

    fused_k<<<dim3(1024),dim3(512),0,stream>>>(hIn, ha1W1, ha1W1 + 1024*512, ha1b1, g1W, psT, pdT, Wx);
    edge2_k<<<dim3(4,256),dim3(256),0,stream>>>(psT, pdT, wd1, bd+0, gum + (size_t)(i*2+0)*EDG*2, AdjT);
    adj_k<<<dim3(512),dim3(512),0,stream>>>(AdjT, Wx, g1b, commT);

    fused_k<<<dim3(1024),dim3(512),0,stream>>>(commT, ha2W1, ha2W1 + 1024*512, ha2b1, g2W, psT, pdT, Wx);
    edge2_k<<<dim3(4,256),dim3(256),0,stream>>>(psT, pdT, wd2, bd+1, gum + (size_t)(i*2+1)*EDG*2, AdjT);
    adj_k<<<dim3(512),dim3(512),0,stream>>>(AdjT, Wx, g2b, commT);

    combine2_k<<<dim3(512),dim3(512),0,stream>>>(hIn, commT, Wf + (size_t)i*HDIM*HDIM, Wc + (size_t)i*HDIM*HDIM,
                                                 xeT, bfp + i*HDIM, bcp + i*HDIM, hOut);
  }

  outinit_k<<<dim3(25),dim3(256),0,stream>>>(out, ba, ls, bvp);
  outpart_k<<<dim3(4,16),dim3(64),0,stream>>>(hA, Wa, Wv, out);
}